// Round 4
// baseline (661.707 us; speedup 1.0000x reference)
//
#include <hip/hip_runtime.h>
#include <hip/hip_fp16.h>

#define C_   256
#define H_   224
#define W_   224
#define HW_  (224 * 224)
#define NWH  28
#define NWW  28
#define NPAIR 1568            // 4 * 28 * 14 window pairs (ww even|odd)
#define NTILE 64              // 48 qkv tiles + 16 out-proj tiles
#define NFRAG (NTILE * 8 * 64)

typedef _Float16 f16x8 __attribute__((ext_vector_type(8)));
typedef float    f32x4 __attribute__((ext_vector_type(4)));

// ---- weight fp32 -> fragment-major fp16 (B-frag for mfma_f32_16x16x32_f16) --
// frag f = (tile*8 + kk)*64 + lane ; value j = W[tile*16 + (lane&15)][kk*32 + (lane>>4)*8 + j]
__global__ void wcvt_kernel(const float* __restrict__ wqkv,
                            const float* __restrict__ wout,
                            _Float16* __restrict__ dst) {
  int f = blockIdx.x * blockDim.x + threadIdx.x;
  if (f >= NFRAG) return;
  int lane = f & 63, kk = (f >> 6) & 7, tile = f >> 9;
  int row = tile * 16 + (lane & 15);
  int col = kk * 32 + (lane >> 4) * 8;
  const float* src = (tile < 48) ? (wqkv + row * 256 + col)
                                 : (wout + (row - 768) * 256 + col);
  f32x4 a = *(const f32x4*)src;
  f32x4 b2 = *(const f32x4*)(src + 4);
  f16x8 r;
#pragma unroll
  for (int q = 0; q < 4; ++q) { r[q] = (_Float16)a[q]; r[q + 4] = (_Float16)b2[q]; }
  *(f16x8*)(dst + (size_t)f * 8) = r;
}

// ---- swizzled LDS accessors (bijective XOR in byte[6:4]; 16B-aligned) -------
__device__ __forceinline__ _Float16* xn_at(char* s, int row, int col) {
  return (_Float16*)(s + ((row * 512 + col * 2) ^ ((row & 7) << 4)));
}
__device__ __forceinline__ _Float16* qk_at(char* b, int row, int col) {
  return (_Float16*)(b + ((row * 64 + col * 2) ^ (((row >> 1) & 3) << 4)));
}
__device__ __forceinline__ _Float16* p_at(char* b, int row, int col) {
  return (_Float16*)(b + ((row * 128 + col * 2) ^ ((row & 7) << 4)));
}
__device__ __forceinline__ _Float16* vt_at(char* b, int d, int k) {
  return (_Float16*)(b + ((d * 128 + k * 2) ^ ((d & 7) << 4)));
}

template <bool USE_WS>
__device__ __forceinline__ f16x8 bfrag(const _Float16* __restrict__ w16,
                                       const float* __restrict__ wqkv,
                                       const float* __restrict__ wout,
                                       int gt, int kk, int lane) {
  if constexpr (USE_WS) {
    return *(const f16x8*)(w16 + ((size_t)((gt * 8 + kk) * 64 + lane)) * 8);
  } else {
    int row = gt * 16 + (lane & 15);
    int col = kk * 32 + (lane >> 4) * 8;
    const float* src = (gt < 48) ? (wqkv + row * 256 + col)
                                 : (wout + (row - 768) * 256 + col);
    f32x4 a = *(const f32x4*)src;
    f32x4 b2 = *(const f32x4*)(src + 4);
    f16x8 r;
#pragma unroll
    for (int q = 0; q < 4; ++q) { r[q] = (_Float16)a[q]; r[q + 4] = (_Float16)b2[q]; }
    return r;
  }
}

// ---- fused window attention: 1 block = 2 windows (ww pair), 512 thr = 8 waves
// LDS (163840 B = 160 KiB exactly -> 1 block/CU, 8 waves):
//   [0,32768)        xnA fp16 [64 tok][256 ch] swizzled; reused as merged-oA
//   [32768,65536)    xnB likewise
//   [65536,163840)   per-wave scratch, wave w at 65536 + w*12288:
//       [0,4096) q [64][32] | [4096,8192) k [64][32] | [8192,12288) vT [32][64]
//       p [64][64] overlays q+k after scores
//   LN reduction (5 KB) overlays scratch during phases 2-3.
template <bool USE_WS>
__global__ __launch_bounds__(512, 2) void winattn_kernel(
    const float* __restrict__ x, const float* __restrict__ gamma,
    const float* __restrict__ beta, const float* __restrict__ wqkv32,
    const float* __restrict__ bqkv, const float* __restrict__ wout32,
    const float* __restrict__ bout, const _Float16* __restrict__ w16,
    float* __restrict__ out) {
  extern __shared__ char smem[];
  float* red = (float*)(smem + 65536);  // [2 win][sum|sq][4][64] = 1024 f
  float* mrs = red + 1024;              // [2 win][mu|rstd][64]   = 256 f

  // XCD swizzle: 1568 = 8*196; XCD x gets a contiguous pair range.
  const int n0 = blockIdx.x;
  const int n  = (n0 & 7) * (NPAIR / 8) + (n0 >> 3);
  const int b   = n / (NWH * (NWW / 2));
  const int rem = n % (NWH * (NWW / 2));
  const int wh  = rem / (NWW / 2);
  const int wwA = (rem % (NWW / 2)) * 2;  // even; pair covers wwA, wwA+1
  const int tid  = threadIdx.x;
  const int w    = tid >> 6;    // wave 0..7
  const int lane = tid & 63;
  const int lr   = lane & 15;
  const int lg   = lane >> 4;

  // ---- phase 1: cooperative staging, fully-coalesced float4 reads ----
  {
    const float* xbase = x + ((size_t)(b * C_) * H_ + wh * 8) * W_ + wwA * 8;
    const int px4 = (lane & 3) * 4;      // 0,4,8,12 across the 16-px pair span
    const int row = (lane >> 2) & 7;     // 0..7
    const int chh = lane >> 5;           // 0..1
    char* xw = smem + ((px4 >> 3) * 32768);  // window A or B (uniform per lane)
    const int pc = px4 & 7;              // col within window
#pragma unroll
    for (int cc = 0; cc < 16; ++cc) {
      const int ch = w * 32 + cc * 2 + chh;
      f32x4 v = *(const f32x4*)(xbase + (size_t)ch * HW_ + row * W_ + px4);
#pragma unroll
      for (int i = 0; i < 4; ++i)
        *xn_at(xw, row * 8 + pc + i, ch) = (_Float16)v[i];
    }
  }
  __syncthreads();

  // ---- phase 2: LN partial sums (wave w: window w>>2, channels (w&3)*64..) --
  const int win = w >> 2;
  const int w4  = w & 3;
  char* xw = smem + win * 32768;
  {
    const int c0 = w4 * 64;
    float sum = 0.f, sq = 0.f;
#pragma unroll
    for (int j = 0; j < 8; ++j) {
      f16x8 hv = *(const f16x8*)xn_at(xw, lane, c0 + j * 8);
#pragma unroll
      for (int jj = 0; jj < 8; ++jj) {
        float f = (float)hv[jj];
        sum += f; sq += f * f;
      }
    }
    red[(win * 4 + w4) * 64 + lane] = sum;
    red[512 + (win * 4 + w4) * 64 + lane] = sq;
  }
  __syncthreads();

  // ---- phase 2b: LN stats ----
  if (tid < 128) {
    const int wn = tid >> 6, t = tid & 63;
    float s = 0.f, s2 = 0.f;
#pragma unroll
    for (int i = 0; i < 4; ++i) {
      s  += red[(wn * 4 + i) * 64 + t];
      s2 += red[512 + (wn * 4 + i) * 64 + t];
    }
    float mu  = s * (1.f / 256.f);
    float var = s2 * (1.f / 256.f) - mu * mu;
    mrs[wn * 128 + t]      = mu;
    mrs[wn * 128 + 64 + t] = rsqrtf(var + 1e-5f);
  }
  __syncthreads();

  // ---- phase 3: normalize in place ----
  {
    const int c0 = w4 * 64;
    const float mu = mrs[win * 128 + lane], rs = mrs[win * 128 + 64 + lane];
#pragma unroll
    for (int j = 0; j < 8; ++j) {
      f16x8 hv = *(const f16x8*)xn_at(xw, lane, c0 + j * 8);
      f32x4 g0 = *(const f32x4*)(gamma + c0 + j * 8);
      f32x4 g1 = *(const f32x4*)(gamma + c0 + j * 8 + 4);
      f32x4 b0 = *(const f32x4*)(beta + c0 + j * 8);
      f32x4 b1 = *(const f32x4*)(beta + c0 + j * 8 + 4);
#pragma unroll
      for (int jj = 0; jj < 4; ++jj) {
        hv[jj]     = (_Float16)(((float)hv[jj] - mu) * rs * g0[jj] + b0[jj]);
        hv[jj + 4] = (_Float16)(((float)hv[jj + 4] - mu) * rs * g1[jj] + b1[jj]);
      }
      *(f16x8*)xn_at(xw, lane, c0 + j * 8) = hv;
    }
  }
  __syncthreads();

  // ---- phase 4+5: per-wave head-local QKV + attention (no barriers) ----
  char* scr   = smem + 65536 + w * 12288;
  char* kbase = scr + 4096;
  char* vbase = scr + 8192;
  f32x4 oacc[2][4][2];
  f32x4 oinv2[2][4];
  const float sc_q = 0.17677669529663687f;  // 1/sqrt(32)

#pragma unroll
  for (int hl = 0; hl < 2; ++hl) {
    const int hcol  = (2 * w4 + hl) * 32;
    const int tbase = w4 * 4 + hl * 2;
    f32x4 acc[6][4];
#pragma unroll
    for (int t = 0; t < 6; ++t)
#pragma unroll
      for (int mi = 0; mi < 4; ++mi) acc[t][mi] = (f32x4){0.f, 0.f, 0.f, 0.f};
#pragma unroll
    for (int kk = 0; kk < 8; ++kk) {
      f16x8 af[4];
#pragma unroll
      for (int mi = 0; mi < 4; ++mi)
        af[mi] = *(const f16x8*)xn_at(xw, mi * 16 + lr, kk * 32 + lg * 8);
#pragma unroll
      for (int t = 0; t < 6; ++t) {
        const int gt = (t >> 1) * 16 + tbase + (t & 1);
        f16x8 bf = bfrag<USE_WS>(w16, wqkv32, wout32, gt, kk, lane);
#pragma unroll
        for (int mi = 0; mi < 4; ++mi)
          acc[t][mi] = __builtin_amdgcn_mfma_f32_16x16x32_f16(af[mi], bf, acc[t][mi], 0, 0, 0);
      }
    }
    // epilogues: q scaled+bias, k bias, v bias transposed
#pragma unroll
    for (int t2 = 0; t2 < 2; ++t2) {
      const float bq = bqkv[hcol + t2 * 16 + lr];
      const float bk = bqkv[256 + hcol + t2 * 16 + lr];
      const float bv = bqkv[512 + hcol + t2 * 16 + lr];
#pragma unroll
      for (int mi = 0; mi < 4; ++mi)
#pragma unroll
        for (int i = 0; i < 4; ++i) {
          const int trow = mi * 16 + lg * 4 + i;
          *qk_at(scr,   trow, t2 * 16 + lr) = (_Float16)((acc[t2][mi][i] + bq) * sc_q);
          *qk_at(kbase, trow, t2 * 16 + lr) = (_Float16)(acc[2 + t2][mi][i] + bk);
          *vt_at(vbase, t2 * 16 + lr, trow) = (_Float16)(acc[4 + t2][mi][i] + bv);
        }
    }
    // scores = q @ k^T
    f16x8 qa[4], kb[4];
#pragma unroll
    for (int mi = 0; mi < 4; ++mi)
      qa[mi] = *(const f16x8*)qk_at(scr, mi * 16 + lr, lg * 8);
#pragma unroll
    for (int ni = 0; ni < 4; ++ni)
      kb[ni] = *(const f16x8*)qk_at(kbase, ni * 16 + lr, lg * 8);
    f32x4 sc[4][4];
#pragma unroll
    for (int mi = 0; mi < 4; ++mi)
#pragma unroll
      for (int ni = 0; ni < 4; ++ni) {
        f32x4 z = {0.f, 0.f, 0.f, 0.f};
        sc[mi][ni] = __builtin_amdgcn_mfma_f32_16x16x32_f16(qa[mi], kb[ni], z, 0, 0, 0);
      }
    // softmax (row r = mi*16+lg*4+i lives in the 16 lanes of group lg)
#pragma unroll
    for (int mi = 0; mi < 4; ++mi)
#pragma unroll
      for (int i = 0; i < 4; ++i) {
        float m = fmaxf(fmaxf(sc[mi][0][i], sc[mi][1][i]),
                        fmaxf(sc[mi][2][i], sc[mi][3][i]));
        m = fmaxf(m, __shfl_xor(m, 1));
        m = fmaxf(m, __shfl_xor(m, 2));
        m = fmaxf(m, __shfl_xor(m, 4));
        m = fmaxf(m, __shfl_xor(m, 8));
        float s = 0.f;
#pragma unroll
        for (int ni = 0; ni < 4; ++ni) {
          float e = __expf(sc[mi][ni][i] - m);
          sc[mi][ni][i] = e;
          s += e;
        }
        s += __shfl_xor(s, 1);
        s += __shfl_xor(s, 2);
        s += __shfl_xor(s, 4);
        s += __shfl_xor(s, 8);
        oinv2[hl][mi][i] = 1.f / s;
      }
    // p (unnormalized) -> LDS, overlaying q+k
#pragma unroll
    for (int mi = 0; mi < 4; ++mi)
#pragma unroll
      for (int ni = 0; ni < 4; ++ni)
#pragma unroll
        for (int i = 0; i < 4; ++i)
          *p_at(scr, mi * 16 + lg * 4 + i, ni * 16 + lr) = (_Float16)sc[mi][ni][i];
    // PV
#pragma unroll
    for (int mi = 0; mi < 4; ++mi)
#pragma unroll
      for (int nt2 = 0; nt2 < 2; ++nt2)
        oacc[hl][mi][nt2] = (f32x4){0.f, 0.f, 0.f, 0.f};
#pragma unroll
    for (int ks2 = 0; ks2 < 2; ++ks2) {
      f16x8 pa[4];
#pragma unroll
      for (int mi = 0; mi < 4; ++mi)
        pa[mi] = *(const f16x8*)p_at(scr, mi * 16 + lr, ks2 * 32 + lg * 8);
#pragma unroll
      for (int nt2 = 0; nt2 < 2; ++nt2) {
        f16x8 vb = *(const f16x8*)vt_at(vbase, nt2 * 16 + lr, ks2 * 32 + lg * 8);
#pragma unroll
        for (int mi = 0; mi < 4; ++mi)
          oacc[hl][mi][nt2] = __builtin_amdgcn_mfma_f32_16x16x32_f16(
              pa[mi], vb, oacc[hl][mi][nt2], 0, 0, 0);
      }
    }
#pragma unroll
    for (int mi = 0; mi < 4; ++mi)
#pragma unroll
      for (int nt2 = 0; nt2 < 2; ++nt2)
#pragma unroll
        for (int i = 0; i < 4; ++i)
          oacc[hl][mi][nt2][i] *= oinv2[hl][mi][i];
  }
  __syncthreads();  // all waves done reading xn

  // ---- phase 6: merged-head o -> own window's xn ----
#pragma unroll
  for (int hl = 0; hl < 2; ++hl) {
    const int hcol = (2 * w4 + hl) * 32;
#pragma unroll
    for (int mi = 0; mi < 4; ++mi)
#pragma unroll
      for (int nt2 = 0; nt2 < 2; ++nt2)
#pragma unroll
        for (int i = 0; i < 4; ++i)
          *xn_at(xw, mi * 16 + lg * 4 + i, hcol + nt2 * 16 + lr) =
              (_Float16)oacc[hl][mi][nt2][i];
  }
  __syncthreads();

  // ---- phase 7: out projection for BOTH windows; full-line stores ----
  {
    f32x4 acc[2][2][4];  // [win][ntl][mi]
#pragma unroll
    for (int wi = 0; wi < 2; ++wi)
#pragma unroll
      for (int t = 0; t < 2; ++t)
#pragma unroll
        for (int mi = 0; mi < 4; ++mi) acc[wi][t][mi] = (f32x4){0.f, 0.f, 0.f, 0.f};
#pragma unroll
    for (int kk = 0; kk < 8; ++kk) {
      f16x8 afA[4], afB[4];
#pragma unroll
      for (int mi = 0; mi < 4; ++mi) {
        afA[mi] = *(const f16x8*)xn_at(smem, mi * 16 + lr, kk * 32 + lg * 8);
        afB[mi] = *(const f16x8*)xn_at(smem + 32768, mi * 16 + lr, kk * 32 + lg * 8);
      }
#pragma unroll
      for (int ntl = 0; ntl < 2; ++ntl) {
        f16x8 bf = bfrag<USE_WS>(w16, wqkv32, wout32, 48 + w * 2 + ntl, kk, lane);
#pragma unroll
        for (int mi = 0; mi < 4; ++mi) {
          acc[0][ntl][mi] = __builtin_amdgcn_mfma_f32_16x16x32_f16(afA[mi], bf, acc[0][ntl][mi], 0, 0, 0);
          acc[1][ntl][mi] = __builtin_amdgcn_mfma_f32_16x16x32_f16(afB[mi], bf, acc[1][ntl][mi], 0, 0, 0);
        }
      }
    }
#pragma unroll
    for (int ntl = 0; ntl < 2; ++ntl) {
      const int och = w * 32 + ntl * 16 + lr;
      const float bias = bout[och];
      float* ob = out + ((size_t)(b * C_ + och) * H_ + wh * 8) * W_ + wwA * 8;
#pragma unroll
      for (int mi = 0; mi < 4; ++mi) {
        const int tb  = mi * 16 + lg * 4;
        const int ro  = (tb >> 3) * W_ + (tb & 7);
        f32x4 ovA, ovB;
#pragma unroll
        for (int i = 0; i < 4; ++i) {
          ovA[i] = acc[0][ntl][mi][i] + bias;
          ovB[i] = acc[1][ntl][mi][i] + bias;
        }
        *(f32x4*)&ob[ro]     = ovA;   // cols [0,8) of the pair span
        *(f32x4*)&ob[ro + 8] = ovB;   // cols [8,16) -> full 64B line dirty
      }
    }
  }
}

extern "C" void kernel_launch(void* const* d_in, const int* in_sizes, int n_in,
                              void* d_out, int out_size, void* d_ws, size_t ws_size,
                              hipStream_t stream) {
  (void)in_sizes; (void)n_in; (void)out_size;
  const float* x     = (const float*)d_in[0];
  const float* gamma = (const float*)d_in[1];
  const float* beta  = (const float*)d_in[2];
  const float* wqkv  = (const float*)d_in[3];
  const float* bqkv  = (const float*)d_in[4];
  const float* wout  = (const float*)d_in[5];
  const float* bout  = (const float*)d_in[6];
  float* out = (float*)d_out;

  const size_t need_ws = (size_t)NFRAG * 8 * sizeof(_Float16);  // 512 KB
  const int shmem = 163840;

  if (ws_size >= need_ws) {
    _Float16* w16 = (_Float16*)d_ws;
    wcvt_kernel<<<NFRAG / 256, 256, 0, stream>>>(wqkv, wout, w16);
    static int attr_set = 0;
    if (!attr_set) {
      (void)hipFuncSetAttribute((const void*)winattn_kernel<true>,
                                hipFuncAttributeMaxDynamicSharedMemorySize, shmem);
      attr_set = 1;
    }
    winattn_kernel<true><<<NPAIR, 512, shmem, stream>>>(
        x, gamma, beta, wqkv, bqkv, wout, bout, w16, out);
  } else {
    static int attr_set2 = 0;
    if (!attr_set2) {
      (void)hipFuncSetAttribute((const void*)winattn_kernel<false>,
                                hipFuncAttributeMaxDynamicSharedMemorySize, shmem);
      attr_set2 = 1;
    }
    winattn_kernel<false><<<NPAIR, 512, shmem, stream>>>(
        x, gamma, beta, wqkv, bqkv, wout, bout, (const _Float16*)nullptr, out);
  }
}